// Round 14
// baseline (217.369 us; speedup 1.0000x reference)
//
#include <hip/hip_runtime.h>
#include <math.h>

#define N_NODES 100000
#define N_EDGES 3200000
#define LO_BITS 7
#define NPB 128                               // nodes per bucket (dst & 127, dst >> 7)
#define NB  ((N_NODES + NPB - 1) / NPB)       // 782 buckets
#define PART_B 512                            // partition blocks (CPB/NB ~= 8 edges/run)
#define PART_T 1024
#define CPB (N_EDGES / PART_B)                // 6250 edges per partition block (exact)
#define PNIT ((CPB + PART_T - 1) / PART_T)    // 7 iterations
#define BCAP 5120                             // staged bucket capacity (avg 4092, ~8 sigma)
#define CMAX 10                               // reg-held edges per thread (512*10 = BCAP)

typedef unsigned long long u64;
typedef unsigned int u32;
typedef unsigned short u16;

// float <-> bf16 (round-to-nearest-even)
static __device__ inline u16 f2bf(float f) {
    u32 u = __float_as_uint(f);
    return (u16)((u + 0x7FFF + ((u >> 16) & 1)) >> 16);
}
static __device__ inline float bf2f(u16 h) {
    return __uint_as_float((u32)h << 16);
}

// inclusive wave-scan over 64 lanes (1 shfl-chain, no barriers)
static __device__ inline int wave_iscan(int x, int lane) {
#pragma unroll
    for (int off = 1; off < 64; off <<= 1) {
        int u = __shfl_up(x, off, 64);
        if (lane >= off) x += u;
    }
    return x;
}

// ---------------- stage 1: multisplit into 782 buckets (NO global atomics) ----------

// dual per-wave-parity sub-histograms + register-batched loads (all 7 iterations'
// dst values in flight before the atomic chain starts — phase is latency-bound).
__global__ void __launch_bounds__(PART_T) hist_k(const int* __restrict__ dst,
                                                 int* __restrict__ hist_mat) {
    __shared__ int h[2][NB];
    for (int t = threadIdx.x; t < 2 * NB; t += blockDim.x) h[0][t] = 0;
    __syncthreads();
    int par = (threadIdx.x >> 6) & 1;         // wave parity
    int base = blockIdx.x * CPB;
    int dl[PNIT];
#pragma unroll
    for (int it = 0; it < PNIT; it++) {
        int e = base + it * PART_T + threadIdx.x;
        if (e < base + CPB) dl[it] = dst[e];
    }
#pragma unroll
    for (int it = 0; it < PNIT; it++) {
        int e = base + it * PART_T + threadIdx.x;
        if (e < base + CPB) atomicAdd(&h[par][dl[it] >> LO_BITS], 1);
    }
    __syncthreads();
    for (int t = threadIdx.x; t < NB; t += blockDim.x)
        hist_mat[blockIdx.x * NB + t] = h[0][t] + h[1][t];
}

// column-wise exclusive scan over the 512 partition blocks: one block per bin.
// Writes to SEPARATE hist_excl (raw hist_mat preserved for part_k's local scan).
__global__ void __launch_bounds__(PART_B) colscan_k(const int* __restrict__ hist_mat,
                                                    int* __restrict__ hist_excl,
                                                    int* __restrict__ tot) {
    __shared__ int wsum[PART_B / 64];
    int bin = blockIdx.x, t = threadIdx.x;
    int lane = t & 63, w = t >> 6;
    int v = hist_mat[t * NB + bin];
    int x = wave_iscan(v, lane);
    if (lane == 63) wsum[w] = x;
    __syncthreads();
    int base = 0;
#pragma unroll
    for (int i = 0; i < PART_B / 64; i++)
        if (i < w) base += wsum[i];
    hist_excl[t * NB + bin] = base + x - v;   // exclusive within column
    if (t == PART_B - 1) tot[bin] = base + x;
}

// LDS-staged sorted partition: block-local counting sort, then run-coalesced output.
// Packed staging word: [63:47] src (17b) | [46:30] dst (17b) | [29:0] w bits [31:2].
// base_k FOLDED IN. Phase B register-batches the 21 global loads (7 it x dst/src/w)
// before the atomic+ds_write chain — the phase is load-latency-bound (VALUBusy ~3%).
// NOTE r12 lesson: CPB/NB must stay >= 8 edges (one 64B line per run).
__global__ void __launch_bounds__(PART_T) part_k(
        const int* __restrict__ src, const int* __restrict__ dst,
        const float* __restrict__ w, const int* __restrict__ hist_mat,
        const int* __restrict__ hist_excl, const int* __restrict__ tot,
        u64* __restrict__ ebuf, int* __restrict__ bbase) {
    __shared__ u64 sorted[CPB];               // 50.0 KB
    __shared__ int cur[NB];                   // 3.1 KB (cursor; starts at lscan)
    __shared__ int gofs[NB];                  // 3.1 KB
    __shared__ int swA[PART_T / 64];
    __shared__ int swB[PART_T / 64];
    int t = threadIdx.x;
    int lane = t & 63, wv = t >> 6;
    int base = blockIdx.x * CPB;
    // phase A': dual 782-wide wave-scan — own histogram row AND tot[] (for bbase)
    int rawc = (t < NB) ? hist_mat[blockIdx.x * NB + t] : 0;
    int totv = (t < NB) ? tot[t] : 0;
    int xA = wave_iscan(rawc, lane);
    int xB = wave_iscan(totv, lane);
    if (lane == 63) { swA[wv] = xA; swB[wv] = xB; }
    __syncthreads();
    int bsA = 0, bsB = 0;
#pragma unroll
    for (int i = 0; i < PART_T / 64; i++)
        if (i < wv) { bsA += swA[i]; bsB += swB[i]; }
    if (t < NB) {
        int lscan = bsA + xA - rawc;          // block-local exclusive offset
        int bb    = bsB + xB - totv;          // exclusive scan of tot = bbase[t]
        cur[t] = lscan;
        gofs[t] = bb + hist_excl[blockIdx.x * NB + t] - lscan;
        if (blockIdx.x == 0) bbase[t] = bb;
    }
    if (blockIdx.x == 0 && t == 0) bbase[NB] = N_EDGES;
    __syncthreads();
    // phase B: register-batch loads, then scatter into LDS in bin-sorted order
    int dl[PNIT], sl[PNIT];
    u32 wl[PNIT];
#pragma unroll
    for (int it = 0; it < PNIT; it++) {
        int e = base + it * PART_T + t;
        if (e < base + CPB) {
            dl[it] = dst[e];
            sl[it] = __builtin_nontemporal_load(&src[e]);
            wl[it] = __float_as_uint(__builtin_nontemporal_load(&w[e]));
        }
    }
#pragma unroll
    for (int it = 0; it < PNIT; it++) {
        int e = base + it * PART_T + t;
        if (e < base + CPB) {
            int d = dl[it];
            int pos = atomicAdd(&cur[d >> LO_BITS], 1);   // LDS atomic
            sorted[pos] = ((u64)(u32)sl[it] << 47) | ((u64)(u32)d << 30)
                        | (u64)(wl[it] >> 2);
        }
    }
    __syncthreads();
    // phase C: stream out — consecutive lanes share runs, addresses monotonic
    for (int p = t; p < CPB; p += PART_T) {
        u64 pk = sorted[p];
        int sv = (int)(pk >> 47);
        int d  = (int)((pk >> 30) & 0x1FFFF);
        u32 wvv = ((u32)pk & 0x3FFFFFFF) << 2;
        u32 hi = ((u32)sv << LO_BITS) | (u32)(d & (NPB - 1));
        ebuf[gofs[d >> LO_BITS] + p] = ((u64)hi << 32) | (u64)wvv;
    }
}

// ---------------- stage 2: per-bucket CSR-ization + degree (one block per bucket) ----
// ORDINAL TRICK: pass 1's packed returning atomic (cnt in [63:40], wsum fixed-point
// in [39:0]) hands back the edge's per-node ordinal — pass 2 places each main edge
// at excl[node]+ordinal with ZERO atomics. Guard edges (stat-impossible) use a
// separate counter + cursor; totals stay exact. dinv rel. error ~1e-8 as before.
__global__ void __launch_bounds__(512) csr_deg_k(
        const u64* __restrict__ ebuf, const int* __restrict__ bbase,
        int* __restrict__ row_ptr, float* __restrict__ dinv,
        u64* __restrict__ pedge) {
    __shared__ u64 staged[BCAP];              // 40 KB
    __shared__ u64 cwp[NPB];                  // packed cnt|wsum (main edges)
    __shared__ u64 cwp2[NPB];                 // packed cnt|wsum (guard edges, ~0)
    __shared__ int exs[NPB];                  // exclusive offsets
    __shared__ int gcur[NPB];                 // guard cursor
    __shared__ int cw[2];
    int b = blockIdx.x, t = threadIdx.x;
    if (t < NPB) { cwp[t] = 0ULL; cwp2[t] = 0ULL; }
    __syncthreads();
    int j0 = bbase[b], j1 = bbase[b + 1];
    // pass 1: edges -> regs; returning packed atomic captures per-node ordinal
    u64 pe[CMAX];
    int od[CMAX];
    int nit = 0;
#pragma unroll
    for (int it = 0; it < CMAX; it++) {
        int j = j0 + it * 512 + t;
        if (j < j1) {
            u64 e = ebuf[j];
            pe[it] = e;
            int lo = (int)((u32)(e >> 32) & (NPB - 1));
            float wf = __uint_as_float((u32)e);
            u64 old = atomicAdd(&cwp[lo],
                                ((u64)1 << 40) | (u64)(wf * 134217728.0f + 0.5f));
            od[it] = (int)(old >> 40);
            nit = it + 1;
        }
    }
    // overflow guard (bucket > BCAP edges — statistically impossible, kept for safety)
    for (int j = j0 + 512 * CMAX + t; j < j1; j += 512) {
        u64 e = ebuf[j];
        int lo = (int)((u32)(e >> 32) & (NPB - 1));
        float wf = __uint_as_float((u32)e);
        atomicAdd(&cwp2[lo], ((u64)1 << 40) | (u64)(wf * 134217728.0f + 0.5f));
    }
    __syncthreads();
    // exclusive wave-scan of total cnt[0..NPB) (2 waves + tiny fixup)
    int lane = t & 63;
    int v = 0, v1c = 0;
    float ws = 0.0f;
    if (t < NPB) {
        u64 c1 = cwp[t], c2 = cwp2[t];
        v1c = (int)(c1 >> 40);
        v = v1c + (int)(c2 >> 40);
        u64 wsum40 = (c1 & 0xFFFFFFFFFFULL) + (c2 & 0xFFFFFFFFFFULL);
        ws = (float)wsum40 * (1.0f / 134217728.0f);
    }
    int x = wave_iscan(v, lane);
    if (t < NPB && lane == 63) cw[t >> 6] = x;
    __syncthreads();
    if (t < NPB) {
        int incl = x + ((t >= 64) ? cw[0] : 0);
        int excl = incl - v;
        exs[t] = excl;
        gcur[t] = excl + v1c;                 // guard slots start after main edges
        int node = b * NPB + t;
        if (node < N_NODES) {
            row_ptr[node] = j0 + excl;
            dinv[node] = rsqrtf(1.0f + ws);                  // self-loop weight 1
        }
    }
    if (b == NB - 1 && t == 0) row_ptr[N_NODES] = N_EDGES;
    __syncthreads();
    // pass 2: place main edges at excl+ordinal — NO atomics
#pragma unroll
    for (int it = 0; it < CMAX; it++) {
        if (it < nit) {
            u64 e = pe[it];
            u32 hi = (u32)(e >> 32);
            int lo = (int)(hi & (NPB - 1));
            int p = exs[lo] + od[it];
            u64 val = ((u64)(hi >> LO_BITS) << 32) | (u64)(u32)e;   // (src, raw w)
            if (p < BCAP) staged[p] = val;
            else pedge[j0 + p] = val;                        // stat-impossible fallback
        }
    }
    for (int j = j0 + 512 * CMAX + t; j < j1; j += 512) {    // overflow guard
        u64 e = ebuf[j];
        u32 hi = (u32)(e >> 32);
        int lo = (int)(hi & (NPB - 1));
        int p = atomicAdd(&gcur[lo], 1);
        u64 val = ((u64)(hi >> LO_BITS) << 32) | (u64)(u32)e;
        if (p < BCAP) staged[p] = val;
        else pedge[j0 + p] = val;
    }
    __syncthreads();
    // coalesced stream-out
    int nbe = j1 - j0;
    int lim = nbe < BCAP ? nbe : BCAP;
    for (int p = t; p < lim; p += 512) pedge[j0 + p] = staged[p];
}

// ---------------- dense / gather kernels ----------------

// g1 = bf16( (x @ W1) * dinv[node] ) — x rows staged once through LDS (no 16x re-read)
__global__ void __launch_bounds__(256) gemm1(
        const float* __restrict__ x, const float* __restrict__ W1,
        const float* __restrict__ dinv, u16* __restrict__ g1b) {
    __shared__ float sW[64 * 16];
    __shared__ float xs[16][68];              // 16 nodes/block, +4 pad vs 64
    for (int t = threadIdx.x; t < 64 * 16; t += blockDim.x) sW[t] = W1[t];
    int nbase = blockIdx.x * 16;              // 6250 blocks x 16 nodes = exact
    // stage 16 rows coalesced: 256 threads x 1 float4 each
    {
        int q = threadIdx.x;                  // [0,256): node q>>4, float4 (q&15)
        const float4 v = ((const float4*)(x + (size_t)nbase * 64))[q];
        int n = q >> 4, f4 = q & 15;
        xs[n][f4 * 4 + 0] = v.x;
        xs[n][f4 * 4 + 1] = v.y;
        xs[n][f4 * 4 + 2] = v.z;
        xs[n][f4 * 4 + 3] = v.w;
    }
    __syncthreads();
    int n = threadIdx.x >> 4, c = threadIdx.x & 15;
    int node = nbase + n;
    float acc = 0.0f;
#pragma unroll
    for (int k = 0; k < 64; k++) acc += xs[n][k] * sW[k * 16 + c];
    g1b[node * 16 + c] = f2bf(acc * dinv[node]);
}

// conv1 gather: FOUR threads per node, 4 private feature accumulators each.
// pedge via ALIGNED 16B uint4 loads; 8-edge main loop keeps ~12 loads in flight
// (4 uint4 pedge + 8 uint2 g1w) to cover the ~200cy L2-hit latency of random
// g1w reads; falls through to 4-edge loop + scalar tail.
__global__ void __launch_bounds__(256) gather1(
        const int* __restrict__ row_ptr, const u64* __restrict__ pedge,
        const float* __restrict__ dinv, const u32* __restrict__ g1w,
        const float* __restrict__ b1, const float* __restrict__ W2,
        float* __restrict__ y2) {
    int gid = blockIdx.x * blockDim.x + threadIdx.x;
    int node = gid >> 2;
    if (node >= N_NODES) return;
    int q = gid & 3;                          // feature quad: f = 4q .. 4q+3
    int j0 = row_ptr[node], j1 = row_ptr[node + 1];
    float a0 = 0.0f, a1 = 0.0f, a2 = 0.0f, a3 = 0.0f;
    int j = j0;
    // peel one edge if j0 is odd -> j becomes even (pedge + j is 16B aligned)
    if ((j & 1) && j < j1) {
        u64 pe = pedge[j];
        int s = (int)(pe >> 32);
        uint2 g = *(const uint2*)(g1w + (size_t)s * 8 + q * 2);
        float wv = __uint_as_float((u32)pe);
        a0 += bf2f((u16)g.x) * wv;  a1 += bf2f((u16)(g.x >> 16)) * wv;
        a2 += bf2f((u16)g.y) * wv;  a3 += bf2f((u16)(g.y >> 16)) * wv;
        j++;
    }
    // deep main loop: 8 edges per iteration (4x uint4 + 8 independent g1 loads)
    for (; j + 8 <= j1; j += 8) {
        uint4 pA = *(const uint4*)(pedge + j);
        uint4 pB = *(const uint4*)(pedge + j + 2);
        uint4 pC = *(const uint4*)(pedge + j + 4);
        uint4 pD = *(const uint4*)(pedge + j + 6);
        int s0 = (int)pA.y, s1 = (int)pA.w, s2 = (int)pB.y, s3 = (int)pB.w;
        int s4 = (int)pC.y, s5 = (int)pC.w, s6 = (int)pD.y, s7 = (int)pD.w;
        uint2 g0 = *(const uint2*)(g1w + (size_t)s0 * 8 + q * 2);
        uint2 g1v = *(const uint2*)(g1w + (size_t)s1 * 8 + q * 2);
        uint2 g2v = *(const uint2*)(g1w + (size_t)s2 * 8 + q * 2);
        uint2 g3v = *(const uint2*)(g1w + (size_t)s3 * 8 + q * 2);
        uint2 g4v = *(const uint2*)(g1w + (size_t)s4 * 8 + q * 2);
        uint2 g5v = *(const uint2*)(g1w + (size_t)s5 * 8 + q * 2);
        uint2 g6v = *(const uint2*)(g1w + (size_t)s6 * 8 + q * 2);
        uint2 g7v = *(const uint2*)(g1w + (size_t)s7 * 8 + q * 2);
        float w0 = __uint_as_float(pA.x), w1 = __uint_as_float(pA.z);
        float w2 = __uint_as_float(pB.x), w3 = __uint_as_float(pB.z);
        float w4 = __uint_as_float(pC.x), w5 = __uint_as_float(pC.z);
        float w6 = __uint_as_float(pD.x), w7 = __uint_as_float(pD.z);
        a0 += bf2f((u16)g0.x) * w0;   a1 += bf2f((u16)(g0.x >> 16)) * w0;
        a2 += bf2f((u16)g0.y) * w0;   a3 += bf2f((u16)(g0.y >> 16)) * w0;
        a0 += bf2f((u16)g1v.x) * w1;  a1 += bf2f((u16)(g1v.x >> 16)) * w1;
        a2 += bf2f((u16)g1v.y) * w1;  a3 += bf2f((u16)(g1v.y >> 16)) * w1;
        a0 += bf2f((u16)g2v.x) * w2;  a1 += bf2f((u16)(g2v.x >> 16)) * w2;
        a2 += bf2f((u16)g2v.y) * w2;  a3 += bf2f((u16)(g2v.y >> 16)) * w2;
        a0 += bf2f((u16)g3v.x) * w3;  a1 += bf2f((u16)(g3v.x >> 16)) * w3;
        a2 += bf2f((u16)g3v.y) * w3;  a3 += bf2f((u16)(g3v.y >> 16)) * w3;
        a0 += bf2f((u16)g4v.x) * w4;  a1 += bf2f((u16)(g4v.x >> 16)) * w4;
        a2 += bf2f((u16)g4v.y) * w4;  a3 += bf2f((u16)(g4v.y >> 16)) * w4;
        a0 += bf2f((u16)g5v.x) * w5;  a1 += bf2f((u16)(g5v.x >> 16)) * w5;
        a2 += bf2f((u16)g5v.y) * w5;  a3 += bf2f((u16)(g5v.y >> 16)) * w5;
        a0 += bf2f((u16)g6v.x) * w6;  a1 += bf2f((u16)(g6v.x >> 16)) * w6;
        a2 += bf2f((u16)g6v.y) * w6;  a3 += bf2f((u16)(g6v.y >> 16)) * w6;
        a0 += bf2f((u16)g7v.x) * w7;  a1 += bf2f((u16)(g7v.x >> 16)) * w7;
        a2 += bf2f((u16)g7v.y) * w7;  a3 += bf2f((u16)(g7v.y >> 16)) * w7;
    }
    // 4-edge loop for remainder
    for (; j + 4 <= j1; j += 4) {
        uint4 pA = *(const uint4*)(pedge + j);
        uint4 pB = *(const uint4*)(pedge + j + 2);
        int s0 = (int)pA.y, s1 = (int)pA.w, s2 = (int)pB.y, s3 = (int)pB.w;
        uint2 g0 = *(const uint2*)(g1w + (size_t)s0 * 8 + q * 2);
        uint2 g1v = *(const uint2*)(g1w + (size_t)s1 * 8 + q * 2);
        uint2 g2v = *(const uint2*)(g1w + (size_t)s2 * 8 + q * 2);
        uint2 g3v = *(const uint2*)(g1w + (size_t)s3 * 8 + q * 2);
        float w0 = __uint_as_float(pA.x), w1 = __uint_as_float(pA.z);
        float w2 = __uint_as_float(pB.x), w3 = __uint_as_float(pB.z);
        a0 += bf2f((u16)g0.x) * w0;   a1 += bf2f((u16)(g0.x >> 16)) * w0;
        a2 += bf2f((u16)g0.y) * w0;   a3 += bf2f((u16)(g0.y >> 16)) * w0;
        a0 += bf2f((u16)g1v.x) * w1;  a1 += bf2f((u16)(g1v.x >> 16)) * w1;
        a2 += bf2f((u16)g1v.y) * w1;  a3 += bf2f((u16)(g1v.y >> 16)) * w1;
        a0 += bf2f((u16)g2v.x) * w2;  a1 += bf2f((u16)(g2v.x >> 16)) * w2;
        a2 += bf2f((u16)g2v.y) * w2;  a3 += bf2f((u16)(g2v.y >> 16)) * w2;
        a0 += bf2f((u16)g3v.x) * w3;  a1 += bf2f((u16)(g3v.x >> 16)) * w3;
        a2 += bf2f((u16)g3v.y) * w3;  a3 += bf2f((u16)(g3v.y >> 16)) * w3;
    }
    // tail (0..3 edges)
    for (; j < j1; j++) {
        u64 pe = pedge[j];
        int s = (int)(pe >> 32);
        uint2 g = *(const uint2*)(g1w + (size_t)s * 8 + q * 2);
        float wv = __uint_as_float((u32)pe);
        a0 += bf2f((u16)g.x) * wv;  a1 += bf2f((u16)(g.x >> 16)) * wv;
        a2 += bf2f((u16)g.y) * wv;  a3 += bf2f((u16)(g.y >> 16)) * wv;
    }
    // self-loop (g1 = h1*dinv already)
    uint2 gs = *(const uint2*)(g1w + (size_t)node * 8 + q * 2);
    a0 += bf2f((u16)gs.x);  a1 += bf2f((u16)(gs.x >> 16));
    a2 += bf2f((u16)gs.y);  a3 += bf2f((u16)(gs.y >> 16));
    float di = dinv[node];
    int f0 = q * 4;
    float v0 = a0 * di + b1[f0];     v0 = v0 > 0.0f ? v0 : 0.0f;
    float v1 = a1 * di + b1[f0 + 1]; v1 = v1 > 0.0f ? v1 : 0.0f;
    float v2 = a2 * di + b1[f0 + 2]; v2 = v2 > 0.0f ? v2 : 0.0f;
    float v3 = a3 * di + b1[f0 + 3]; v3 = v3 > 0.0f ? v3 : 0.0f;
    // fused gemm2 partials over this thread's 4 features
    float p0 = v0 * W2[2 * f0]     + v1 * W2[2 * f0 + 2]
             + v2 * W2[2 * f0 + 4] + v3 * W2[2 * f0 + 6];
    float p1 = v0 * W2[2 * f0 + 1] + v1 * W2[2 * f0 + 3]
             + v2 * W2[2 * f0 + 5] + v3 * W2[2 * f0 + 7];
    // combine the 4 feature-quad lanes (gid-contiguous -> lane-contiguous)
    p0 += __shfl_xor(p0, 1, 64);  p1 += __shfl_xor(p1, 1, 64);
    p0 += __shfl_xor(p0, 2, 64);  p1 += __shfl_xor(p1, 2, 64);
    if (q == 0) {
        y2[node * 2]     = p0 * di;           // pre-scale for layer 2
        y2[node * 2 + 1] = p1 * di;
    }
}

// conv2 gather: TWO threads per node, ALIGNED 16B uint4 loads (2 edges/lane/iter,
// 4 edges per pair-iteration), even-peel + scalar tail, one shfl to combine,
// head fused on the even lane.
__global__ void __launch_bounds__(256) gather2(
        const int* __restrict__ row_ptr, const u64* __restrict__ pedge,
        const float* __restrict__ dinv, const float* __restrict__ y2,
        const float* __restrict__ b2, const float* __restrict__ lin_w,
        const float* __restrict__ lin_b, float* __restrict__ out) {
    int gid = blockIdx.x * blockDim.x + threadIdx.x;
    int i = gid >> 1;
    if (i >= N_NODES) return;
    int h = gid & 1;
    int j0 = row_ptr[i], j1 = row_ptr[i + 1];
    float a0 = 0.0f, a1 = 0.0f;
    int j = j0;
    // peel one edge if j0 is odd (lane 0 handles it) -> j becomes even
    if ((j & 1) && j < j1) {
        if (h == 0) {
            u64 pe = pedge[j];
            int s = (int)(pe >> 32);
            float wr = __uint_as_float((u32)pe);
            float2 yv = *(const float2*)(y2 + (size_t)s * 2);
            a0 += yv.x * wr;
            a1 += yv.y * wr;
        }
        j++;
    }
    // main: 4 edges per pair-iteration; lane h takes edges j+2h, j+2h+1 (one uint4)
    for (; j + 4 <= j1; j += 4) {
        uint4 p = *(const uint4*)(pedge + j + 2 * h);
        int sA = (int)p.y, sB = (int)p.w;
        float wA = __uint_as_float(p.x), wB = __uint_as_float(p.z);
        float2 yA = *(const float2*)(y2 + (size_t)sA * 2);
        float2 yB = *(const float2*)(y2 + (size_t)sB * 2);
        a0 += yA.x * wA + yB.x * wB;
        a1 += yA.y * wA + yB.y * wB;
    }
    // tail (0..3 edges): alternate by lane
    for (int jj = j + h; jj < j1; jj += 2) {
        u64 pe = pedge[jj];
        int s = (int)(pe >> 32);
        float wr = __uint_as_float((u32)pe);
        float2 yv = *(const float2*)(y2 + (size_t)s * 2);
        a0 += yv.x * wr;
        a1 += yv.y * wr;
    }
    a0 += __shfl_xor(a0, 1, 64);
    a1 += __shfl_xor(a1, 1, 64);
    if (h == 0) {
        float di = dinv[i];
        float y0 = y2[i * 2], y1 = y2[i * 2 + 1];
        float x20 = (a0 + y0) * di + b2[0];
        float x21 = (a1 + y1) * di + b2[1];
        out[N_NODES + i * 2]     = x20;
        out[N_NODES + i * 2 + 1] = x21;
        float r0 = x20 > 0.0f ? x20 : 0.0f;
        float r1 = x21 > 0.0f ? x21 : 0.0f;
        float z = r0 * lin_w[0] + r1 * lin_w[1] + lin_b[0];
        out[i] = 1.0f / (1.0f + expf(-z));
    }
}

extern "C" void kernel_launch(void* const* d_in, const int* in_sizes, int n_in,
                              void* d_out, int out_size, void* d_ws, size_t ws_size,
                              hipStream_t stream) {
    const float* x     = (const float*)d_in[0];
    const int*   ei    = (const int*)d_in[1];   // [2, E] flattened
    const float* ew    = (const float*)d_in[2];
    const float* W1    = (const float*)d_in[3];
    const float* b1    = (const float*)d_in[4];
    const float* W2    = (const float*)d_in[5];
    const float* b2    = (const float*)d_in[6];
    const float* lin_w = (const float*)d_in[7];
    const float* lin_b = (const float*)d_in[8];
    float* out = (float*)d_out;

    const int* src = ei;
    const int* dst = ei + N_EDGES;

    // ---- workspace carve-up (g1b/y2 alias the dead ebuf region, DISJOINTLY) ----
    char* w8 = (char*)d_ws;
    size_t off = 0;
    auto take = [&](size_t bytes) { char* p = w8 + off; off += (bytes + 15) & ~((size_t)15); return (void*)p; };
    u64*   ebuf      = (u64*)  take((size_t)N_EDGES * 8);       // 25.6 MB (dead after csr_deg_k)
    u64*   pedge     = (u64*)  take((size_t)N_EDGES * 8);       // 25.6 MB
    int*   hist_mat  = (int*)  take((size_t)PART_B * NB * 4);   // 1.6 MB (raw counts)
    int*   hist_excl = (int*)  take((size_t)PART_B * NB * 4);   // 1.6 MB (col-exclusive)
    int*   tot       = (int*)  take((size_t)NB * 4);
    int*   bbase     = (int*)  take((size_t)(NB + 1) * 4);
    int*   row_ptr   = (int*)  take((size_t)(N_NODES + 1) * 4);
    float* dinv      = (float*)take((size_t)N_NODES * 4);
    u16*   g1b       = (u16*)ebuf;                              // bytes [0, 3.2MB)
    u32*   g1w       = (u32*)ebuf;                              // u32 view of the same table
    float* y2        = (float*)ebuf + (size_t)8 * N_NODES;      // bytes [3.2MB, 4.0MB)

    const int B = 256;

    // stage 1: multisplit to 782 buckets (zero global atomics; LDS-sorted writes)
    hist_k<<<PART_B, PART_T, 0, stream>>>(dst, hist_mat);
    colscan_k<<<NB, PART_B, 0, stream>>>(hist_mat, hist_excl, tot);
    part_k<<<PART_B, PART_T, 0, stream>>>(src, dst, ew, hist_mat, hist_excl, tot,
                                          ebuf, bbase);

    // stage 2: per-bucket CSR + degree (single ebuf pass, ordinal-placed, no P2 atomics)
    csr_deg_k<<<NB, 512, 0, stream>>>(ebuf, bbase, row_ptr, dinv, pedge);

    // layer 1 (norm algebraically folded: g1 pre-scaled by dinv[src]; bf16 table)
    gemm1<<<N_NODES / 16, B, 0, stream>>>(x, W1, dinv, g1b);
    gather1<<<(4 * N_NODES + B - 1) / B, B, 0, stream>>>(row_ptr, pedge, dinv, g1w, b1, W2, y2);

    // layer 2 + head
    gather2<<<(2 * N_NODES + B - 1) / B, B, 0, stream>>>(row_ptr, pedge, dinv, y2, b2,
                                                        lin_w, lin_b, out);
}

// Round 15
// 209.750 us; speedup vs baseline: 1.0363x; 1.0363x over previous
//
#include <hip/hip_runtime.h>
#include <math.h>

#define N_NODES 100000
#define N_EDGES 3200000
#define LO_BITS 7
#define NPB 128                               // nodes per bucket (dst & 127, dst >> 7)
#define NB  ((N_NODES + NPB - 1) / NPB)       // 782 buckets
#define PART_B 512                            // partition blocks (CPB/NB ~= 8 edges/run)
#define PART_T 1024
#define CPB (N_EDGES / PART_B)                // 6250 edges per partition block (exact)
#define PNIT ((CPB + PART_T - 1) / PART_T)    // 7 iterations
#define BCAP 5120                             // staged bucket capacity (avg 4092, ~8 sigma)
#define CMAX 10                               // reg-held edges per thread (512*10 = BCAP)

typedef unsigned long long u64;
typedef unsigned int u32;
typedef unsigned short u16;

// float <-> bf16 (round-to-nearest-even)
static __device__ inline u16 f2bf(float f) {
    u32 u = __float_as_uint(f);
    return (u16)((u + 0x7FFF + ((u >> 16) & 1)) >> 16);
}
static __device__ inline float bf2f(u16 h) {
    return __uint_as_float((u32)h << 16);
}

// inclusive wave-scan over 64 lanes (1 shfl-chain, no barriers)
static __device__ inline int wave_iscan(int x, int lane) {
#pragma unroll
    for (int off = 1; off < 64; off <<= 1) {
        int u = __shfl_up(x, off, 64);
        if (lane >= off) x += u;
    }
    return x;
}

// ---------------- stage 1: multisplit into 782 buckets (NO global atomics) ----------

// dual per-wave-parity sub-histograms + register-batched loads
__global__ void __launch_bounds__(PART_T) hist_k(const int* __restrict__ dst,
                                                 int* __restrict__ hist_mat) {
    __shared__ int h[2][NB];
    for (int t = threadIdx.x; t < 2 * NB; t += blockDim.x) h[0][t] = 0;
    __syncthreads();
    int par = (threadIdx.x >> 6) & 1;         // wave parity
    int base = blockIdx.x * CPB;
    int dl[PNIT];
#pragma unroll
    for (int it = 0; it < PNIT; it++) {
        int e = base + it * PART_T + threadIdx.x;
        if (e < base + CPB) dl[it] = dst[e];
    }
#pragma unroll
    for (int it = 0; it < PNIT; it++) {
        int e = base + it * PART_T + threadIdx.x;
        if (e < base + CPB) atomicAdd(&h[par][dl[it] >> LO_BITS], 1);
    }
    __syncthreads();
    for (int t = threadIdx.x; t < NB; t += blockDim.x)
        hist_mat[blockIdx.x * NB + t] = h[0][t] + h[1][t];
}

// column-wise exclusive scan over the 512 partition blocks: one block per bin.
__global__ void __launch_bounds__(PART_B) colscan_k(const int* __restrict__ hist_mat,
                                                    int* __restrict__ hist_excl,
                                                    int* __restrict__ tot) {
    __shared__ int wsum[PART_B / 64];
    int bin = blockIdx.x, t = threadIdx.x;
    int lane = t & 63, w = t >> 6;
    int v = hist_mat[t * NB + bin];
    int x = wave_iscan(v, lane);
    if (lane == 63) wsum[w] = x;
    __syncthreads();
    int base = 0;
#pragma unroll
    for (int i = 0; i < PART_B / 64; i++)
        if (i < w) base += wsum[i];
    hist_excl[t * NB + bin] = base + x - v;   // exclusive within column
    if (t == PART_B - 1) tot[bin] = base + x;
}

// LDS-staged sorted partition (base_k folded in; r12: CPB/NB >= 8 edges/run).
__global__ void __launch_bounds__(PART_T) part_k(
        const int* __restrict__ src, const int* __restrict__ dst,
        const float* __restrict__ w, const int* __restrict__ hist_mat,
        const int* __restrict__ hist_excl, const int* __restrict__ tot,
        u64* __restrict__ ebuf, int* __restrict__ bbase) {
    __shared__ u64 sorted[CPB];               // 50.0 KB
    __shared__ int cur[NB];                   // 3.1 KB (cursor; starts at lscan)
    __shared__ int gofs[NB];                  // 3.1 KB
    __shared__ int swA[PART_T / 64];
    __shared__ int swB[PART_T / 64];
    int t = threadIdx.x;
    int lane = t & 63, wv = t >> 6;
    int base = blockIdx.x * CPB;
    // phase A': dual 782-wide wave-scan — own histogram row AND tot[] (for bbase)
    int rawc = (t < NB) ? hist_mat[blockIdx.x * NB + t] : 0;
    int totv = (t < NB) ? tot[t] : 0;
    int xA = wave_iscan(rawc, lane);
    int xB = wave_iscan(totv, lane);
    if (lane == 63) { swA[wv] = xA; swB[wv] = xB; }
    __syncthreads();
    int bsA = 0, bsB = 0;
#pragma unroll
    for (int i = 0; i < PART_T / 64; i++)
        if (i < wv) { bsA += swA[i]; bsB += swB[i]; }
    if (t < NB) {
        int lscan = bsA + xA - rawc;          // block-local exclusive offset
        int bb    = bsB + xB - totv;          // exclusive scan of tot = bbase[t]
        cur[t] = lscan;
        gofs[t] = bb + hist_excl[blockIdx.x * NB + t] - lscan;
        if (blockIdx.x == 0) bbase[t] = bb;
    }
    if (blockIdx.x == 0 && t == 0) bbase[NB] = N_EDGES;
    __syncthreads();
    // phase B: register-batch loads, then scatter into LDS in bin-sorted order
    int dl[PNIT], sl[PNIT];
    u32 wl[PNIT];
#pragma unroll
    for (int it = 0; it < PNIT; it++) {
        int e = base + it * PART_T + t;
        if (e < base + CPB) {
            dl[it] = dst[e];
            sl[it] = __builtin_nontemporal_load(&src[e]);
            wl[it] = __float_as_uint(__builtin_nontemporal_load(&w[e]));
        }
    }
#pragma unroll
    for (int it = 0; it < PNIT; it++) {
        int e = base + it * PART_T + t;
        if (e < base + CPB) {
            int d = dl[it];
            int pos = atomicAdd(&cur[d >> LO_BITS], 1);   // LDS atomic
            sorted[pos] = ((u64)(u32)sl[it] << 47) | ((u64)(u32)d << 30)
                        | (u64)(wl[it] >> 2);
        }
    }
    __syncthreads();
    // phase C: stream out — consecutive lanes share runs, addresses monotonic
    for (int p = t; p < CPB; p += PART_T) {
        u64 pk = sorted[p];
        int sv = (int)(pk >> 47);
        int d  = (int)((pk >> 30) & 0x1FFFF);
        u32 wvv = ((u32)pk & 0x3FFFFFFF) << 2;
        u32 hi = ((u32)sv << LO_BITS) | (u32)(d & (NPB - 1));
        ebuf[gofs[d >> LO_BITS] + p] = ((u64)hi << 32) | (u64)wvv;
    }
}

// ---------------- stage 2: per-bucket CSR-ization + degree (one block per bucket) ----
// ORDINAL TRICK: pass 1's returning packed atomic hands back each edge's per-node
// ordinal; pass 2 places main edges at excl+ordinal with zero atomics.
__global__ void __launch_bounds__(512) csr_deg_k(
        const u64* __restrict__ ebuf, const int* __restrict__ bbase,
        int* __restrict__ row_ptr, float* __restrict__ dinv,
        u64* __restrict__ pedge) {
    __shared__ u64 staged[BCAP];              // 40 KB
    __shared__ u64 cwp[NPB];                  // packed cnt|wsum (main edges)
    __shared__ u64 cwp2[NPB];                 // packed cnt|wsum (guard edges, ~0)
    __shared__ int exs[NPB];                  // exclusive offsets
    __shared__ int gcur[NPB];                 // guard cursor
    __shared__ int cw[2];
    int b = blockIdx.x, t = threadIdx.x;
    if (t < NPB) { cwp[t] = 0ULL; cwp2[t] = 0ULL; }
    __syncthreads();
    int j0 = bbase[b], j1 = bbase[b + 1];
    u64 pe[CMAX];
    int od[CMAX];
    int nit = 0;
#pragma unroll
    for (int it = 0; it < CMAX; it++) {
        int j = j0 + it * 512 + t;
        if (j < j1) {
            u64 e = ebuf[j];
            pe[it] = e;
            int lo = (int)((u32)(e >> 32) & (NPB - 1));
            float wf = __uint_as_float((u32)e);
            u64 old = atomicAdd(&cwp[lo],
                                ((u64)1 << 40) | (u64)(wf * 134217728.0f + 0.5f));
            od[it] = (int)(old >> 40);
            nit = it + 1;
        }
    }
    for (int j = j0 + 512 * CMAX + t; j < j1; j += 512) {    // guard (stat-impossible)
        u64 e = ebuf[j];
        int lo = (int)((u32)(e >> 32) & (NPB - 1));
        float wf = __uint_as_float((u32)e);
        atomicAdd(&cwp2[lo], ((u64)1 << 40) | (u64)(wf * 134217728.0f + 0.5f));
    }
    __syncthreads();
    int lane = t & 63;
    int v = 0, v1c = 0;
    float ws = 0.0f;
    if (t < NPB) {
        u64 c1 = cwp[t], c2 = cwp2[t];
        v1c = (int)(c1 >> 40);
        v = v1c + (int)(c2 >> 40);
        u64 wsum40 = (c1 & 0xFFFFFFFFFFULL) + (c2 & 0xFFFFFFFFFFULL);
        ws = (float)wsum40 * (1.0f / 134217728.0f);
    }
    int x = wave_iscan(v, lane);
    if (t < NPB && lane == 63) cw[t >> 6] = x;
    __syncthreads();
    if (t < NPB) {
        int incl = x + ((t >= 64) ? cw[0] : 0);
        int excl = incl - v;
        exs[t] = excl;
        gcur[t] = excl + v1c;                 // guard slots start after main edges
        int node = b * NPB + t;
        if (node < N_NODES) {
            row_ptr[node] = j0 + excl;
            dinv[node] = rsqrtf(1.0f + ws);                  // self-loop weight 1
        }
    }
    if (b == NB - 1 && t == 0) row_ptr[N_NODES] = N_EDGES;
    __syncthreads();
#pragma unroll
    for (int it = 0; it < CMAX; it++) {
        if (it < nit) {
            u64 e = pe[it];
            u32 hi = (u32)(e >> 32);
            int lo = (int)(hi & (NPB - 1));
            int p = exs[lo] + od[it];
            u64 val = ((u64)(hi >> LO_BITS) << 32) | (u64)(u32)e;   // (src, raw w)
            if (p < BCAP) staged[p] = val;
            else pedge[j0 + p] = val;
        }
    }
    for (int j = j0 + 512 * CMAX + t; j < j1; j += 512) {    // guard
        u64 e = ebuf[j];
        u32 hi = (u32)(e >> 32);
        int lo = (int)(hi & (NPB - 1));
        int p = atomicAdd(&gcur[lo], 1);
        u64 val = ((u64)(hi >> LO_BITS) << 32) | (u64)(u32)e;
        if (p < BCAP) staged[p] = val;
        else pedge[j0 + p] = val;
    }
    __syncthreads();
    int nbe = j1 - j0;
    int lim = nbe < BCAP ? nbe : BCAP;
    for (int p = t; p < lim; p += 512) pedge[j0 + p] = staged[p];
}

// ---------------- dense / gather kernels ----------------

// g1 = bf16( (x @ W1) * dinv[node] ) — x rows staged once through LDS
__global__ void __launch_bounds__(256) gemm1(
        const float* __restrict__ x, const float* __restrict__ W1,
        const float* __restrict__ dinv, u16* __restrict__ g1b) {
    __shared__ float sW[64 * 16];
    __shared__ float xs[16][68];              // 16 nodes/block, +4 pad vs 64
    for (int t = threadIdx.x; t < 64 * 16; t += blockDim.x) sW[t] = W1[t];
    int nbase = blockIdx.x * 16;              // 6250 blocks x 16 nodes = exact
    {
        int q = threadIdx.x;                  // [0,256): node q>>4, float4 (q&15)
        const float4 v = ((const float4*)(x + (size_t)nbase * 64))[q];
        int n = q >> 4, f4 = q & 15;
        xs[n][f4 * 4 + 0] = v.x;
        xs[n][f4 * 4 + 1] = v.y;
        xs[n][f4 * 4 + 2] = v.z;
        xs[n][f4 * 4 + 3] = v.w;
    }
    __syncthreads();
    int n = threadIdx.x >> 4, c = threadIdx.x & 15;
    int node = nbase + n;
    float acc = 0.0f;
#pragma unroll
    for (int k = 0; k < 64; k++) acc += xs[n][k] * sW[k * 16 + c];
    g1b[node * 16 + c] = f2bf(acc * dinv[node]);
}

// conv1 gather: EIGHT threads per node = 2 edge-halves (ep) x 4 feature-quads (q).
// Each lane walks HALF the node's edges (2 uint4 + 4 uint2 per 8-edge step) —
// halves the serial latency chain vs 4-thread version. shfl_xor(4) merges halves;
// self-loop added post-merge (counted once). Aligned 16B pedge consumption kept.
__global__ void __launch_bounds__(256) gather1(
        const int* __restrict__ row_ptr, const u64* __restrict__ pedge,
        const float* __restrict__ dinv, const u32* __restrict__ g1w,
        const float* __restrict__ b1, const float* __restrict__ W2,
        float* __restrict__ y2) {
    int gid = blockIdx.x * blockDim.x + threadIdx.x;
    int node = gid >> 3;
    if (node >= N_NODES) return;
    int l3 = gid & 7;
    int q  = l3 & 3;                          // feature quad: f = 4q .. 4q+3
    int ep = l3 >> 2;                         // edge half
    int j0 = row_ptr[node], j1 = row_ptr[node + 1];
    float a0 = 0.0f, a1 = 0.0f, a2 = 0.0f, a3 = 0.0f;
    int j = j0;
    // peel one edge if j0 is odd -> j becomes even (ep 0 handles it)
    if ((j & 1) && j < j1) {
        if (ep == 0) {
            u64 pe = pedge[j];
            int s = (int)(pe >> 32);
            uint2 g = *(const uint2*)(g1w + (size_t)s * 8 + q * 2);
            float wv = __uint_as_float((u32)pe);
            a0 += bf2f((u16)g.x) * wv;  a1 += bf2f((u16)(g.x >> 16)) * wv;
            a2 += bf2f((u16)g.y) * wv;  a3 += bf2f((u16)(g.y >> 16)) * wv;
        }
        j++;
    }
    // main loop: 8 edges per iteration; ep takes edges j+4*ep .. j+4*ep+3
    for (; j + 8 <= j1; j += 8) {
        int jb = j + 4 * ep;
        uint4 pA = *(const uint4*)(pedge + jb);        // edges jb, jb+1
        uint4 pB = *(const uint4*)(pedge + jb + 2);    // edges jb+2, jb+3
        int s0 = (int)pA.y, s1 = (int)pA.w, s2 = (int)pB.y, s3 = (int)pB.w;
        uint2 g0 = *(const uint2*)(g1w + (size_t)s0 * 8 + q * 2);
        uint2 g1v = *(const uint2*)(g1w + (size_t)s1 * 8 + q * 2);
        uint2 g2v = *(const uint2*)(g1w + (size_t)s2 * 8 + q * 2);
        uint2 g3v = *(const uint2*)(g1w + (size_t)s3 * 8 + q * 2);
        float w0 = __uint_as_float(pA.x), w1 = __uint_as_float(pA.z);
        float w2 = __uint_as_float(pB.x), w3 = __uint_as_float(pB.z);
        a0 += bf2f((u16)g0.x) * w0;   a1 += bf2f((u16)(g0.x >> 16)) * w0;
        a2 += bf2f((u16)g0.y) * w0;   a3 += bf2f((u16)(g0.y >> 16)) * w0;
        a0 += bf2f((u16)g1v.x) * w1;  a1 += bf2f((u16)(g1v.x >> 16)) * w1;
        a2 += bf2f((u16)g1v.y) * w1;  a3 += bf2f((u16)(g1v.y >> 16)) * w1;
        a0 += bf2f((u16)g2v.x) * w2;  a1 += bf2f((u16)(g2v.x >> 16)) * w2;
        a2 += bf2f((u16)g2v.y) * w2;  a3 += bf2f((u16)(g2v.y >> 16)) * w2;
        a0 += bf2f((u16)g3v.x) * w3;  a1 += bf2f((u16)(g3v.x >> 16)) * w3;
        a2 += bf2f((u16)g3v.y) * w3;  a3 += bf2f((u16)(g3v.y >> 16)) * w3;
    }
    // 4-edge step: ep takes edge pair j+2*ep (one uint4 + 2 uint2 each)
    if (j + 4 <= j1) {
        uint4 pA = *(const uint4*)(pedge + j + 2 * ep);
        int s0 = (int)pA.y, s1 = (int)pA.w;
        uint2 g0 = *(const uint2*)(g1w + (size_t)s0 * 8 + q * 2);
        uint2 g1v = *(const uint2*)(g1w + (size_t)s1 * 8 + q * 2);
        float w0 = __uint_as_float(pA.x), w1 = __uint_as_float(pA.z);
        a0 += bf2f((u16)g0.x) * w0;   a1 += bf2f((u16)(g0.x >> 16)) * w0;
        a2 += bf2f((u16)g0.y) * w0;   a3 += bf2f((u16)(g0.y >> 16)) * w0;
        a0 += bf2f((u16)g1v.x) * w1;  a1 += bf2f((u16)(g1v.x >> 16)) * w1;
        a2 += bf2f((u16)g1v.y) * w1;  a3 += bf2f((u16)(g1v.y >> 16)) * w1;
        j += 4;
    }
    // tail (0..3 edges): alternate by edge parity
    for (int jj = j + ep; jj < j1; jj += 2) {
        u64 pe = pedge[jj];
        int s = (int)(pe >> 32);
        uint2 g = *(const uint2*)(g1w + (size_t)s * 8 + q * 2);
        float wv = __uint_as_float((u32)pe);
        a0 += bf2f((u16)g.x) * wv;  a1 += bf2f((u16)(g.x >> 16)) * wv;
        a2 += bf2f((u16)g.y) * wv;  a3 += bf2f((u16)(g.y >> 16)) * wv;
    }
    // merge edge-halves (lane bit 2 = ep)
    a0 += __shfl_xor(a0, 4, 64);  a1 += __shfl_xor(a1, 4, 64);
    a2 += __shfl_xor(a2, 4, 64);  a3 += __shfl_xor(a3, 4, 64);
    // self-loop (g1 = h1*dinv already) — added AFTER merge, counted once
    uint2 gs = *(const uint2*)(g1w + (size_t)node * 8 + q * 2);
    a0 += bf2f((u16)gs.x);  a1 += bf2f((u16)(gs.x >> 16));
    a2 += bf2f((u16)gs.y);  a3 += bf2f((u16)(gs.y >> 16));
    float di = dinv[node];
    int f0 = q * 4;
    float v0 = a0 * di + b1[f0];     v0 = v0 > 0.0f ? v0 : 0.0f;
    float v1 = a1 * di + b1[f0 + 1]; v1 = v1 > 0.0f ? v1 : 0.0f;
    float v2 = a2 * di + b1[f0 + 2]; v2 = v2 > 0.0f ? v2 : 0.0f;
    float v3 = a3 * di + b1[f0 + 3]; v3 = v3 > 0.0f ? v3 : 0.0f;
    // fused gemm2 partials over this thread's 4 features
    float p0 = v0 * W2[2 * f0]     + v1 * W2[2 * f0 + 2]
             + v2 * W2[2 * f0 + 4] + v3 * W2[2 * f0 + 6];
    float p1 = v0 * W2[2 * f0 + 1] + v1 * W2[2 * f0 + 3]
             + v2 * W2[2 * f0 + 5] + v3 * W2[2 * f0 + 7];
    // combine the 4 feature-quad lanes (lane bits 0-1 = q)
    p0 += __shfl_xor(p0, 1, 64);  p1 += __shfl_xor(p1, 1, 64);
    p0 += __shfl_xor(p0, 2, 64);  p1 += __shfl_xor(p1, 2, 64);
    if (l3 == 0) {
        y2[node * 2]     = p0 * di;           // pre-scale for layer 2
        y2[node * 2 + 1] = p1 * di;
    }
}

// conv2 gather: FOUR threads per node; lane h owns edge pair j+2h per 8-edge
// iteration (one uint4 each). Two shfl levels combine; head fused on h==0.
__global__ void __launch_bounds__(256) gather2(
        const int* __restrict__ row_ptr, const u64* __restrict__ pedge,
        const float* __restrict__ dinv, const float* __restrict__ y2,
        const float* __restrict__ b2, const float* __restrict__ lin_w,
        const float* __restrict__ lin_b, float* __restrict__ out) {
    int gid = blockIdx.x * blockDim.x + threadIdx.x;
    int i = gid >> 2;
    if (i >= N_NODES) return;
    int h = gid & 3;
    int j0 = row_ptr[i], j1 = row_ptr[i + 1];
    float a0 = 0.0f, a1 = 0.0f;
    int j = j0;
    // peel one edge if j0 is odd (h 0 handles it) -> j becomes even
    if ((j & 1) && j < j1) {
        if (h == 0) {
            u64 pe = pedge[j];
            int s = (int)(pe >> 32);
            float wr = __uint_as_float((u32)pe);
            float2 yv = *(const float2*)(y2 + (size_t)s * 2);
            a0 += yv.x * wr;
            a1 += yv.y * wr;
        }
        j++;
    }
    // main: 8 edges per iteration; lane h takes edges j+2h, j+2h+1 (one uint4)
    for (; j + 8 <= j1; j += 8) {
        uint4 p = *(const uint4*)(pedge + j + 2 * h);
        int sA = (int)p.y, sB = (int)p.w;
        float wA = __uint_as_float(p.x), wB = __uint_as_float(p.z);
        float2 yA = *(const float2*)(y2 + (size_t)sA * 2);
        float2 yB = *(const float2*)(y2 + (size_t)sB * 2);
        a0 += yA.x * wA + yB.x * wB;
        a1 += yA.y * wA + yB.y * wB;
    }
    // 4-edge step: h0/h1 take the two uint4s
    if (j + 4 <= j1) {
        if (h < 2) {
            uint4 p = *(const uint4*)(pedge + j + 2 * h);
            int sA = (int)p.y, sB = (int)p.w;
            float wA = __uint_as_float(p.x), wB = __uint_as_float(p.z);
            float2 yA = *(const float2*)(y2 + (size_t)sA * 2);
            float2 yB = *(const float2*)(y2 + (size_t)sB * 2);
            a0 += yA.x * wA + yB.x * wB;
            a1 += yA.y * wA + yB.y * wB;
        }
        j += 4;
    }
    // tail (0..3 edges): alternate by lane
    for (int jj = j + h; jj < j1; jj += 4) {
        u64 pe = pedge[jj];
        int s = (int)(pe >> 32);
        float wr = __uint_as_float((u32)pe);
        float2 yv = *(const float2*)(y2 + (size_t)s * 2);
        a0 += yv.x * wr;
        a1 += yv.y * wr;
    }
    // combine the 4 lanes (lane bits 0-1 = h)
    a0 += __shfl_xor(a0, 1, 64);  a1 += __shfl_xor(a1, 1, 64);
    a0 += __shfl_xor(a0, 2, 64);  a1 += __shfl_xor(a1, 2, 64);
    if (h == 0) {
        float di = dinv[i];
        float y0 = y2[i * 2], y1 = y2[i * 2 + 1];
        float x20 = (a0 + y0) * di + b2[0];
        float x21 = (a1 + y1) * di + b2[1];
        out[N_NODES + i * 2]     = x20;
        out[N_NODES + i * 2 + 1] = x21;
        float r0 = x20 > 0.0f ? x20 : 0.0f;
        float r1 = x21 > 0.0f ? x21 : 0.0f;
        float z = r0 * lin_w[0] + r1 * lin_w[1] + lin_b[0];
        out[i] = 1.0f / (1.0f + expf(-z));
    }
}

extern "C" void kernel_launch(void* const* d_in, const int* in_sizes, int n_in,
                              void* d_out, int out_size, void* d_ws, size_t ws_size,
                              hipStream_t stream) {
    const float* x     = (const float*)d_in[0];
    const int*   ei    = (const int*)d_in[1];   // [2, E] flattened
    const float* ew    = (const float*)d_in[2];
    const float* W1    = (const float*)d_in[3];
    const float* b1    = (const float*)d_in[4];
    const float* W2    = (const float*)d_in[5];
    const float* b2    = (const float*)d_in[6];
    const float* lin_w = (const float*)d_in[7];
    const float* lin_b = (const float*)d_in[8];
    float* out = (float*)d_out;

    const int* src = ei;
    const int* dst = ei + N_EDGES;

    // ---- workspace carve-up (g1b/y2 alias the dead ebuf region, DISJOINTLY) ----
    char* w8 = (char*)d_ws;
    size_t off = 0;
    auto take = [&](size_t bytes) { char* p = w8 + off; off += (bytes + 15) & ~((size_t)15); return (void*)p; };
    u64*   ebuf      = (u64*)  take((size_t)N_EDGES * 8);       // 25.6 MB (dead after csr_deg_k)
    u64*   pedge     = (u64*)  take((size_t)N_EDGES * 8);       // 25.6 MB
    int*   hist_mat  = (int*)  take((size_t)PART_B * NB * 4);   // 1.6 MB (raw counts)
    int*   hist_excl = (int*)  take((size_t)PART_B * NB * 4);   // 1.6 MB (col-exclusive)
    int*   tot       = (int*)  take((size_t)NB * 4);
    int*   bbase     = (int*)  take((size_t)(NB + 1) * 4);
    int*   row_ptr   = (int*)  take((size_t)(N_NODES + 1) * 4);
    float* dinv      = (float*)take((size_t)N_NODES * 4);
    u16*   g1b       = (u16*)ebuf;                              // bytes [0, 3.2MB)
    u32*   g1w       = (u32*)ebuf;                              // u32 view of the same table
    float* y2        = (float*)ebuf + (size_t)8 * N_NODES;      // bytes [3.2MB, 4.0MB)

    const int B = 256;

    // stage 1: multisplit to 782 buckets (zero global atomics; LDS-sorted writes)
    hist_k<<<PART_B, PART_T, 0, stream>>>(dst, hist_mat);
    colscan_k<<<NB, PART_B, 0, stream>>>(hist_mat, hist_excl, tot);
    part_k<<<PART_B, PART_T, 0, stream>>>(src, dst, ew, hist_mat, hist_excl, tot,
                                          ebuf, bbase);

    // stage 2: per-bucket CSR + degree (single ebuf pass, ordinal-placed, no P2 atomics)
    csr_deg_k<<<NB, 512, 0, stream>>>(ebuf, bbase, row_ptr, dinv, pedge);

    // layer 1 (norm algebraically folded: g1 pre-scaled by dinv[src]; bf16 table)
    gemm1<<<N_NODES / 16, B, 0, stream>>>(x, W1, dinv, g1b);
    gather1<<<(8 * N_NODES + B - 1) / B, B, 0, stream>>>(row_ptr, pedge, dinv, g1w, b1, W2, y2);

    // layer 2 + head
    gather2<<<(4 * N_NODES + B - 1) / B, B, 0, stream>>>(row_ptr, pedge, dinv, y2, b2,
                                                        lin_w, lin_b, out);
}